// Round 3
// baseline (2389.032 us; speedup 1.0000x reference)
//
#include <hip/hip_runtime.h>

// IPAttnProcessor cross-modal fused pipeline for MI355X (gfx950).
// fp32 GEMMs emulated with K-concatenated split-bf16: x = hi + lo (bf16 each),
// stored as [hi | lo] along K. A_sp(M x 2K) @ W_spT(N x 2K)^T includes all four
// hi/lo cross terms in ONE plain bf16 GEMM (m97 structure, global_load_lds).

typedef __attribute__((ext_vector_type(8))) short short8;
typedef __attribute__((ext_vector_type(4))) float f32x4;
typedef __attribute__((ext_vector_type(4))) unsigned short us4;
typedef unsigned short u16;
typedef unsigned long long u64t;

__device__ __forceinline__ u16 bhi(float x){
  return (u16)(__builtin_bit_cast(unsigned int, x) >> 16);
}
__device__ __forceinline__ float fromb(u16 h){
  unsigned int u = ((unsigned int)h) << 16;
  return __builtin_bit_cast(float, u);
}
__device__ __forceinline__ void split2(float x, u16& h, u16& l){
  h = bhi(x);
  l = bhi(x - fromb(h));
}
__device__ __forceinline__ f32x4 mf16(short8 a, short8 b, f32x4 c){
  return __builtin_amdgcn_mfma_f32_16x16x32_bf16(a, b, c, 0, 0, 0);
}

union Frag { short8 s; u64t u[2]; };

// ---------------------------------------------------------------------------
// convert fp32 rows (M x K) -> split rows (M x 2K bf16): [m][k]=hi, [m][K+k]=lo
// ---------------------------------------------------------------------------
__global__ __launch_bounds__(256)
void convert_split_rows(const float* __restrict__ A, u16* __restrict__ Asp, int K)
{
  long idx = (long)blockIdx.x * 256 + threadIdx.x;
  long row = idx / (K / 4);
  int  k4  = (int)(idx % (K / 4)) * 4;
  float4 v = *(const float4*)(A + row * K + k4);
  us4 h, l; u16 hh, ll;
  split2(v.x, hh, ll); h[0]=hh; l[0]=ll;
  split2(v.y, hh, ll); h[1]=hh; l[1]=ll;
  split2(v.z, hh, ll); h[2]=hh; l[2]=ll;
  split2(v.w, hh, ll); h[3]=hh; l[3]=ll;
  *(us4*)(Asp + row * 2L * K + k4)     = h;
  *(us4*)(Asp + row * 2L * K + K + k4) = l;
}

// ---------------------------------------------------------------------------
// W (K x N fp32) -> WT_sp (N x 2K bf16): [n][k]=hi, [n][K+k]=lo (LDS transpose)
// ---------------------------------------------------------------------------
__global__ __launch_bounds__(256)
void transpose_split(const float* __restrict__ W, u16* __restrict__ WT, int K, int N)
{
  __shared__ float t[32][33];
  const int bx = blockIdx.x;   // along N
  const int by = blockIdx.y;   // along K
  const int tx = threadIdx.x & 31, ty = threadIdx.x >> 5;  // 32 x 8
  #pragma unroll
  for (int i = 0; i < 4; ++i){
    int r = by*32 + ty + i*8;   // k
    int c = bx*32 + tx;         // n
    t[ty + i*8][tx] = W[(long)r * N + c];
  }
  __syncthreads();
  #pragma unroll
  for (int i = 0; i < 4; ++i){
    int n = bx*32 + ty + i*8;
    int k = by*32 + tx;
    float v = t[tx][ty + i*8];
    u16 h, l; split2(v, h, l);
    WT[(long)n * 2 * K + k]     = h;
    WT[(long)n * 2 * K + K + k] = l;
  }
}

// ---------------------------------------------------------------------------
// Plain bf16 GEMM, m97 structure: 128x128 tile, BK=64, 4 waves (2x2),
// global_load_lds width-16 staging, linear LDS. M,N mult of 128; K2 mult 64.
// MODE 0: C = ushort split-out (hi at col, lo at col+KH), ldc = 2*KH
// MODE 1: C = fp32, + bias + residual
// ---------------------------------------------------------------------------
template<int MODE>
__global__ __launch_bounds__(256)
void gemm_bf16(const u16* __restrict__ A, int lda,
               const u16* __restrict__ B, int ldb,
               void* __restrict__ Cv, int ldc, int KH,
               int K2, int mTiles, int nwg8,
               const float* __restrict__ bias,
               const float* __restrict__ res, int ldres)
{
  int id = blockIdx.x;
  id = (id & 7) * nwg8 + (id >> 3);   // bijective XCD swizzle (nwg % 8 == 0)
  const int bm = (id % mTiles) * 128;
  const int bn = (id / mTiles) * 128;

  const int tid = threadIdx.x, lane = tid & 63, w = tid >> 6;
  const int wm = w >> 1, wn = w & 1;
  const int r16 = lane & 15, g = lane >> 4;
  const int srow = lane >> 3;          // 0..7 row within 8-row chunk
  const int scol = (lane & 7) * 8;     // 0..56 bf16 col

  __shared__ u16 As[128 * 64];
  __shared__ u16 Bs[128 * 64];

  f32x4 acc[4][4];
  #pragma unroll
  for (int i = 0; i < 4; ++i)
    #pragma unroll
    for (int j = 0; j < 4; ++j)
      acc[i][j] = (f32x4){0.f, 0.f, 0.f, 0.f};

  for (int kt = 0; kt < K2; kt += 64){
    #pragma unroll
    for (int i = 0; i < 4; ++i){
      const u16* src = A + (long)(bm + w*32 + i*8 + srow) * lda + kt + scol;
      __builtin_amdgcn_global_load_lds(
          (const __attribute__((address_space(1))) unsigned int*)src,
          (__attribute__((address_space(3))) unsigned int*)(As + (w*32 + i*8) * 64),
          16, 0, 0);
    }
    #pragma unroll
    for (int i = 0; i < 4; ++i){
      const u16* src = B + (long)(bn + w*32 + i*8 + srow) * ldb + kt + scol;
      __builtin_amdgcn_global_load_lds(
          (const __attribute__((address_space(1))) unsigned int*)src,
          (__attribute__((address_space(3))) unsigned int*)(Bs + (w*32 + i*8) * 64),
          16, 0, 0);
    }
    __syncthreads();

    #pragma unroll
    for (int ks = 0; ks < 2; ++ks){
      Frag a[4], b[4];
      #pragma unroll
      for (int mf = 0; mf < 4; ++mf){
        const u16* p = &As[(wm*64 + mf*16 + r16) * 64 + ks*32 + 4*g];
        a[mf].u[0] = *(const u64t*)p;
        a[mf].u[1] = *(const u64t*)(p + 16);
      }
      #pragma unroll
      for (int nf = 0; nf < 4; ++nf){
        const u16* p = &Bs[(wn*64 + nf*16 + r16) * 64 + ks*32 + 4*g];
        b[nf].u[0] = *(const u64t*)p;
        b[nf].u[1] = *(const u64t*)(p + 16);
      }
      #pragma unroll
      for (int mf = 0; mf < 4; ++mf)
        #pragma unroll
        for (int nf = 0; nf < 4; ++nf)
          acc[mf][nf] = mf16(a[mf].s, b[nf].s, acc[mf][nf]);
    }
    __syncthreads();
  }

  // epilogue: C/D layout col = lane&15, row = 4*(lane>>4)+reg
  #pragma unroll
  for (int mf = 0; mf < 4; ++mf){
    #pragma unroll
    for (int r = 0; r < 4; ++r){
      long grow = bm + wm*64 + mf*16 + 4*g + r;
      #pragma unroll
      for (int nf = 0; nf < 4; ++nf){
        int gcol = bn + wn*64 + nf*16 + r16;
        float v = acc[mf][nf][r];
        if (MODE == 0){
          u16* C = (u16*)Cv;
          u16 h, l; split2(v, h, l);
          C[grow * ldc + gcol]      = h;
          C[grow * ldc + KH + gcol] = l;
        } else {
          float* C = (float*)Cv;
          v += bias[gcol] + res[grow * (long)ldres + gcol];
          C[grow * ldc + gcol] = v;
        }
      }
    }
  }
}

// ---------------------------------------------------------------------------
// Round-1 split GEMM (kept for the small K/V and ip projections, M=77 / M=4).
// ---------------------------------------------------------------------------
template<int BIAS, int RES>
__global__ __launch_bounds__(256)
void gemm_split(const float* __restrict__ A, int lda, long strideAz, int M,
                const float* __restrict__ B0, const float* __restrict__ B1,
                int nsplit, int ldb,
                float* __restrict__ C, int ldc, long strideCz,
                int K,
                const float* __restrict__ bias,
                const float* __restrict__ res, int ldres)
{
  const int bn = blockIdx.x * 128;
  const int bm = blockIdx.y * 128;
  A += (long)blockIdx.z * strideAz;
  C += (long)blockIdx.z * strideCz;
  const float* B = B0; int bcol = bn;
  if (bn >= nsplit){ B = B1; bcol = bn - nsplit; }

  const int tid = threadIdx.x;
  const int lane = tid & 63, w = tid >> 6;
  const int wm = w >> 1, wn = w & 1;
  const int r16 = lane & 15, g = lane >> 4;

  __shared__ u16 Ah[128][36], Al[128][36];
  __shared__ u16 Bh[128][36], Bl[128][36];

  int mvalid = M - bm; if (mvalid > 128) mvalid = 128;
  int wv = mvalid - wm*64; wv = wv < 0 ? 0 : (wv > 64 ? 64 : wv);
  const int mfn = (wv + 15) >> 4;

  f32x4 acc[4][4];
  #pragma unroll
  for (int i = 0; i < 4; ++i)
    #pragma unroll
    for (int j = 0; j < 4; ++j)
      acc[i][j] = (f32x4){0.f, 0.f, 0.f, 0.f};

  const int arow = tid >> 3;
  const int acol = (tid & 7) << 2;
  const int brow = tid >> 5;
  const int bcol4 = (tid & 31) << 2;

  for (int kt = 0; kt < K; kt += 32){
    #pragma unroll
    for (int p = 0; p < 4; ++p){
      int r = p*32 + arow;
      float4 v = {0.f,0.f,0.f,0.f};
      if (bm + r < M) v = *(const float4*)(A + (long)(bm + r)*lda + kt + acol);
      us4 vh, vl; u16 hh, ll;
      split2(v.x, hh, ll); vh[0]=hh; vl[0]=ll;
      split2(v.y, hh, ll); vh[1]=hh; vl[1]=ll;
      split2(v.z, hh, ll); vh[2]=hh; vl[2]=ll;
      split2(v.w, hh, ll); vh[3]=hh; vl[3]=ll;
      *(us4*)&Ah[r][acol] = vh;
      *(us4*)&Al[r][acol] = vl;
    }
    #pragma unroll
    for (int p = 0; p < 4; ++p){
      int kk = p*8 + brow;
      float4 v = *(const float4*)(B + (long)(kt + kk)*ldb + bcol + bcol4);
      u16 hh, ll;
      split2(v.x, hh, ll); Bh[bcol4+0][kk]=hh; Bl[bcol4+0][kk]=ll;
      split2(v.y, hh, ll); Bh[bcol4+1][kk]=hh; Bl[bcol4+1][kk]=ll;
      split2(v.z, hh, ll); Bh[bcol4+2][kk]=hh; Bl[bcol4+2][kk]=ll;
      split2(v.w, hh, ll); Bh[bcol4+3][kk]=hh; Bl[bcol4+3][kk]=ll;
    }
    __syncthreads();

    Frag bh[4], bl[4];
    #pragma unroll
    for (int nf = 0; nf < 4; ++nf){
      const u16* p0 = &Bh[wn*64 + nf*16 + r16][4*g];
      bh[nf].u[0] = *(const u64t*)(p0);
      bh[nf].u[1] = *(const u64t*)(p0 + 16);
      const u16* p1 = &Bl[wn*64 + nf*16 + r16][4*g];
      bl[nf].u[0] = *(const u64t*)(p1);
      bl[nf].u[1] = *(const u64t*)(p1 + 16);
    }
    #pragma unroll
    for (int mf = 0; mf < 4; ++mf){
      if (mf < mfn){
        Frag ah, al;
        const u16* p0 = &Ah[wm*64 + mf*16 + r16][4*g];
        ah.u[0] = *(const u64t*)(p0);
        ah.u[1] = *(const u64t*)(p0 + 16);
        const u16* p1 = &Al[wm*64 + mf*16 + r16][4*g];
        al.u[0] = *(const u64t*)(p1);
        al.u[1] = *(const u64t*)(p1 + 16);
        #pragma unroll
        for (int nf = 0; nf < 4; ++nf){
          acc[mf][nf] = mf16(ah.s, bh[nf].s, acc[mf][nf]);
          acc[mf][nf] = mf16(ah.s, bl[nf].s, acc[mf][nf]);
          acc[mf][nf] = mf16(al.s, bh[nf].s, acc[mf][nf]);
        }
      }
    }
    __syncthreads();
  }

  #pragma unroll
  for (int mf = 0; mf < 4; ++mf){
    #pragma unroll
    for (int r = 0; r < 4; ++r){
      int grow = bm + wm*64 + mf*16 + 4*g + r;
      if (grow < M){
        #pragma unroll
        for (int nf = 0; nf < 4; ++nf){
          int gcol = bn + wn*64 + nf*16 + r16;
          float v = acc[mf][nf][r];
          if (BIAS) v += bias[gcol];
          if (RES)  v += res[(long)grow*ldres + gcol];
          C[(long)grow*ldc + gcol] = v;
        }
      }
    }
  }
}

// ---------------------------------------------------------------------------
// Fused dual attention. Q read as pre-split bf16 (M x 2560); output written
// pre-split bf16 (M x 2560) for the out-projection GEMM.
// ---------------------------------------------------------------------------
__global__ __launch_bounds__(256)
void attn_kernel(const u16* __restrict__ Qsp,   // (4*4096, 2560) split
                 const float* __restrict__ kvt, // (4,77,2560) [K|V] fp32
                 const float* __restrict__ ipb, // (4,4,2560)  fp32
                 u16* __restrict__ attn_sp)     // (4*4096, 2560) split out
{
  const int qt = blockIdx.x, h = blockIdx.y, b = blockIdx.z;
  const int tid = threadIdx.x, lane = tid & 63, w = tid >> 6;
  const int r16 = lane & 15, g = lane >> 4;
  const bool do_ip = (b & 1);
  const float scale = 0.125f;

  __shared__ u16 U0[96*68], U1[96*68];
  __shared__ u16 Vth[64*100], Vtl[64*100];
  __shared__ float ipk[4][64], ipv[4][64], pip[64][4];

  {
    int j  = tid >> 4;
    int d4 = (tid & 15) << 2;
    #pragma unroll
    for (int p = 0; p < 6; ++p){
      int jj = p*16 + j;
      float4 kv4 = {0.f,0.f,0.f,0.f}, vv4 = {0.f,0.f,0.f,0.f};
      if (jj < 77){
        const float* src = kvt + (long)(b*77 + jj)*2560 + h*64 + d4;
        kv4 = *(const float4*)(src);
        vv4 = *(const float4*)(src + 1280);
      }
      u16 hh, ll;
      us4 kh, kl;
      split2(kv4.x, hh, ll); kh[0]=hh; kl[0]=ll;
      split2(kv4.y, hh, ll); kh[1]=hh; kl[1]=ll;
      split2(kv4.z, hh, ll); kh[2]=hh; kl[2]=ll;
      split2(kv4.w, hh, ll); kh[3]=hh; kl[3]=ll;
      *(us4*)&U0[jj*68 + d4] = kh;
      *(us4*)&U1[jj*68 + d4] = kl;
      split2(vv4.x, hh, ll); Vth[(d4+0)*100 + jj]=hh; Vtl[(d4+0)*100 + jj]=ll;
      split2(vv4.y, hh, ll); Vth[(d4+1)*100 + jj]=hh; Vtl[(d4+1)*100 + jj]=ll;
      split2(vv4.z, hh, ll); Vth[(d4+2)*100 + jj]=hh; Vtl[(d4+2)*100 + jj]=ll;
      split2(vv4.w, hh, ll); Vth[(d4+3)*100 + jj]=hh; Vtl[(d4+3)*100 + jj]=ll;
    }
  }
  if (do_ip){
    int i = tid >> 6, d = tid & 63;
    const float* src = ipb + (long)(b*4 + i)*2560 + h*64 + d;
    ipk[i][d] = src[0];
    ipv[i][d] = src[1280];
  }
  __syncthreads();

  // ---- Q fragments direct from split-bf16 global ----
  Frag qh[2], ql[2];
  {
    const u16* qrow = Qsp + (long)(b*4096 + qt*64 + w*16 + r16)*2560 + h*64;
    #pragma unroll
    for (int ks = 0; ks < 2; ++ks){
      qh[ks].u[0] = *(const u64t*)(qrow + ks*32 + 4*g);
      qh[ks].u[1] = *(const u64t*)(qrow + ks*32 + 16 + 4*g);
      ql[ks].u[0] = *(const u64t*)(qrow + 1280 + ks*32 + 4*g);
      ql[ks].u[1] = *(const u64t*)(qrow + 1280 + ks*32 + 16 + 4*g);
    }
  }
  f32x4 sacc[6];
  #pragma unroll
  for (int nf = 0; nf < 6; ++nf) sacc[nf] = (f32x4){0.f,0.f,0.f,0.f};
  #pragma unroll
  for (int nf = 0; nf < 6; ++nf){
    #pragma unroll
    for (int ks = 0; ks < 2; ++ks){
      Frag kh, kl;
      const u16* p0 = &U0[(nf*16 + r16)*68 + ks*32 + 4*g];
      kh.u[0] = *(const u64t*)(p0);
      kh.u[1] = *(const u64t*)(p0 + 16);
      const u16* p1 = &U1[(nf*16 + r16)*68 + ks*32 + 4*g];
      kl.u[0] = *(const u64t*)(p1);
      kl.u[1] = *(const u64t*)(p1 + 16);
      sacc[nf] = mf16(qh[ks].s, kh.s, sacc[nf]);
      sacc[nf] = mf16(qh[ks].s, kl.s, sacc[nf]);
      sacc[nf] = mf16(ql[ks].s, kh.s, sacc[nf]);
    }
  }

  float mx[4] = {-1e30f,-1e30f,-1e30f,-1e30f};
  #pragma unroll
  for (int nf = 0; nf < 6; ++nf){
    if (nf*16 + r16 < 77){
      #pragma unroll
      for (int r = 0; r < 4; ++r) mx[r] = fmaxf(mx[r], sacc[nf][r]);
    }
  }
  #pragma unroll
  for (int off = 1; off < 16; off <<= 1){
    #pragma unroll
    for (int r = 0; r < 4; ++r) mx[r] = fmaxf(mx[r], __shfl_xor(mx[r], off));
  }
  float p[6][4];
  float sum[4] = {0.f,0.f,0.f,0.f};
  #pragma unroll
  for (int nf = 0; nf < 6; ++nf){
    bool valid = (nf*16 + r16 < 77);
    #pragma unroll
    for (int r = 0; r < 4; ++r){
      float e = valid ? __expf((sacc[nf][r] - mx[r]) * scale) : 0.f;
      p[nf][r] = e; sum[r] += e;
    }
  }
  #pragma unroll
  for (int off = 1; off < 16; off <<= 1){
    #pragma unroll
    for (int r = 0; r < 4; ++r) sum[r] += __shfl_xor(sum[r], off);
  }
  #pragma unroll
  for (int r = 0; r < 4; ++r) sum[r] = 1.f / sum[r];
  #pragma unroll
  for (int nf = 0; nf < 6; ++nf)
    #pragma unroll
    for (int r = 0; r < 4; ++r) p[nf][r] *= sum[r];

  if (do_ip){
    int rr = tid >> 2, ii = tid & 3;
    const u16* q2 = Qsp + (long)(b*4096 + qt*64 + rr)*2560 + h*64;
    float s = 0.f;
    #pragma unroll
    for (int d4 = 0; d4 < 64; d4 += 4){
      us4 hv = *(const us4*)(q2 + d4);
      us4 lv = *(const us4*)(q2 + 1280 + d4);
      #pragma unroll
      for (int i = 0; i < 4; ++i)
        s += (fromb(hv[i]) + fromb(lv[i])) * ipk[ii][d4 + i];
    }
    float m2 = fmaxf(s, __shfl_xor(s, 1)); m2 = fmaxf(m2, __shfl_xor(m2, 2));
    float e  = __expf((s - m2) * scale);
    float es = e + __shfl_xor(e, 1); es += __shfl_xor(es, 2);
    pip[rr][ii] = e / es;
  }

  __syncthreads();

  #pragma unroll
  for (int nf = 0; nf < 6; ++nf){
    int jc = nf*16 + r16;
    #pragma unroll
    for (int r = 0; r < 4; ++r){
      int qr = w*16 + 4*g + r;
      u16 hh, ll; split2(p[nf][r], hh, ll);
      U0[qr*100 + jc] = hh; U1[qr*100 + jc] = ll;
    }
  }
  __syncthreads();

  f32x4 oacc[4];
  #pragma unroll
  for (int nf = 0; nf < 4; ++nf) oacc[nf] = (f32x4){0.f,0.f,0.f,0.f};
  Frag ph[3], pl[3];
  #pragma unroll
  for (int ks = 0; ks < 3; ++ks){
    const u16* p0 = &U0[(w*16 + r16)*100 + ks*32 + 4*g];
    ph[ks].u[0] = *(const u64t*)(p0);
    ph[ks].u[1] = *(const u64t*)(p0 + 16);
    const u16* p1 = &U1[(w*16 + r16)*100 + ks*32 + 4*g];
    pl[ks].u[0] = *(const u64t*)(p1);
    pl[ks].u[1] = *(const u64t*)(p1 + 16);
  }
  #pragma unroll
  for (int nf = 0; nf < 4; ++nf){
    #pragma unroll
    for (int ks = 0; ks < 3; ++ks){
      Frag vh, vl;
      const u16* p0 = &Vth[(nf*16 + r16)*100 + ks*32 + 4*g];
      vh.u[0] = *(const u64t*)(p0);
      vh.u[1] = *(const u64t*)(p0 + 16);
      const u16* p1 = &Vtl[(nf*16 + r16)*100 + ks*32 + 4*g];
      vl.u[0] = *(const u64t*)(p1);
      vl.u[1] = *(const u64t*)(p1 + 16);
      oacc[nf] = mf16(ph[ks].s, vh.s, oacc[nf]);
      oacc[nf] = mf16(ph[ks].s, vl.s, oacc[nf]);
      oacc[nf] = mf16(pl[ks].s, vh.s, oacc[nf]);
    }
  }

  #pragma unroll
  for (int nf = 0; nf < 4; ++nf){
    int dv = nf*16 + r16;
    #pragma unroll
    for (int r = 0; r < 4; ++r){
      int lr = w*16 + 4*g + r;
      float val = oacc[nf][r];
      if (do_ip){
        val += pip[lr][0]*ipv[0][dv] + pip[lr][1]*ipv[1][dv]
             + pip[lr][2]*ipv[2][dv] + pip[lr][3]*ipv[3][dv];
      }
      u16 hh, ll; split2(val, hh, ll);
      long base = (long)(b*4096 + qt*64 + lr)*2560 + h*64 + dv;
      attn_sp[base]        = hh;
      attn_sp[base + 1280] = ll;
    }
  }
}

// ---------------------------------------------------------------------------
extern "C" void kernel_launch(void* const* d_in, const int* in_sizes, int n_in,
                              void* d_out, int out_size, void* d_ws, size_t ws_size,
                              hipStream_t stream)
{
  const float* hs   = (const float*)d_in[0];
  const float* ehs  = (const float*)d_in[1];
  const float* Wq   = (const float*)d_in[2];
  const float* Wk   = (const float*)d_in[3];
  const float* Wv   = (const float*)d_in[4];
  const float* Wkip = (const float*)d_in[5];
  const float* Wvip = (const float*)d_in[6];
  const float* Wout = (const float*)d_in[7];
  const float* bout = (const float*)d_in[8];
  float* out = (float*)d_out;

  // workspace layout (~100 MB): bufA reused as hs_sp then attn_sp
  u16* bufA  = (u16*)d_ws;                 // 16384 x 2560 bf16
  u16* WqT   = bufA + 16384L * 2560;       // 1280 x 2560
  u16* WoT   = WqT  + 1280L * 2560;        // 1280 x 2560
  float* kvt = (float*)(WoT + 1280L * 2560); // 4 x 77 x 2560
  float* ipb = kvt + 4L * 77 * 2560;         // 4 x 4 x 2560
  u16* Qsp   = (u16*)d_out;                // Q staged split in d_out

  dim3 blk(256);

  // 1. hs -> split (bufA)
  convert_split_rows<<<dim3(20480), blk, 0, stream>>>(hs, bufA, 1280);
  // 2. weight transpose+split
  transpose_split<<<dim3(40,40), blk, 0, stream>>>(Wq,   WqT, 1280, 1280);
  transpose_split<<<dim3(40,40), blk, 0, stream>>>(Wout, WoT, 1280, 1280);
  // 3. small projections (fp32 in, fp32 out)
  gemm_split<0,0><<<dim3(20,1,4), blk, 0, stream>>>(
      ehs, 2048, 81L*2048, 77, Wk, Wv, 1280, 1280,
      kvt, 2560, 77L*2560, 2048, nullptr, nullptr, 0);
  gemm_split<0,0><<<dim3(20,1,4), blk, 0, stream>>>(
      ehs + 77L*2048, 2048, 81L*2048, 4, Wkip, Wvip, 1280, 1280,
      ipb, 2560, 4L*2560, 2048, nullptr, nullptr, 0);
  // 4. Q projection: hs_sp @ WqT -> Qsp (split out, in d_out)
  gemm_bf16<0><<<dim3(1280), blk, 0, stream>>>(
      bufA, 2560, WqT, 2560, (void*)Qsp, 2560, 1280,
      2560, 128, 160, nullptr, nullptr, 0);
  // 5. fused dual attention -> attn_sp (bufA, overwrites hs_sp)
  attn_kernel<<<dim3(64,20,4), blk, 0, stream>>>(Qsp, kvt, ipb, bufA);
  // 6. out projection + bias + residual -> d_out (fp32)
  gemm_bf16<1><<<dim3(1280), blk, 0, stream>>>(
      bufA, 2560, WoT, 2560, (void*)out, 1280, 0,
      2560, 128, 160, bout, hs, 1280);
}

// Round 5
// 935.198 us; speedup vs baseline: 2.5546x; 2.5546x over previous
//
#include <hip/hip_runtime.h>

// IPAttnProcessor cross-modal fused pipeline for MI355X (gfx950).
// fp32 GEMMs emulated with K-concatenated split-bf16: x = hi + lo (bf16 each),
// stored as [hi | lo] along K. A_sp(M x 2K) @ W_spT(N x 2K)^T includes all four
// hi/lo cross terms in ONE plain bf16 GEMM.
// R4: T2 XOR-swizzle on the GEMM LDS tiles (col_u16 ^= (row&7)<<3) with
// pre-swizzled global source for global_load_lds (rule #21), b128 fragment
// reads, and m-major tile order for XCD/L2 locality.

typedef __attribute__((ext_vector_type(8))) short short8;
typedef __attribute__((ext_vector_type(4))) float f32x4;
typedef __attribute__((ext_vector_type(4))) unsigned short us4;
typedef unsigned short u16;
typedef unsigned long long u64t;

__device__ __forceinline__ u16 bhi(float x){
  return (u16)(__builtin_bit_cast(unsigned int, x) >> 16);
}
__device__ __forceinline__ float fromb(u16 h){
  unsigned int u = ((unsigned int)h) << 16;
  return __builtin_bit_cast(float, u);
}
__device__ __forceinline__ void split2(float x, u16& h, u16& l){
  h = bhi(x);
  l = bhi(x - fromb(h));
}
__device__ __forceinline__ f32x4 mf16(short8 a, short8 b, f32x4 c){
  return __builtin_amdgcn_mfma_f32_16x16x32_bf16(a, b, c, 0, 0, 0);
}

union Frag { short8 s; u64t u[2]; };

// ---------------------------------------------------------------------------
// convert fp32 rows (M x K) -> split rows (M x 2K bf16): [m][k]=hi, [m][K+k]=lo
// ---------------------------------------------------------------------------
__global__ __launch_bounds__(256)
void convert_split_rows(const float* __restrict__ A, u16* __restrict__ Asp, int K)
{
  long idx = (long)blockIdx.x * 256 + threadIdx.x;
  long row = idx / (K / 4);
  int  k4  = (int)(idx % (K / 4)) * 4;
  float4 v = *(const float4*)(A + row * K + k4);
  us4 h, l; u16 hh, ll;
  split2(v.x, hh, ll); h[0]=hh; l[0]=ll;
  split2(v.y, hh, ll); h[1]=hh; l[1]=ll;
  split2(v.z, hh, ll); h[2]=hh; l[2]=ll;
  split2(v.w, hh, ll); h[3]=hh; l[3]=ll;
  *(us4*)(Asp + row * 2L * K + k4)     = h;
  *(us4*)(Asp + row * 2L * K + K + k4) = l;
}

// ---------------------------------------------------------------------------
// W (K x N fp32) -> WT_sp (N x 2K bf16): [n][k]=hi, [n][K+k]=lo (LDS transpose)
// ---------------------------------------------------------------------------
__global__ __launch_bounds__(256)
void transpose_split(const float* __restrict__ W, u16* __restrict__ WT, int K, int N)
{
  __shared__ float t[32][33];
  const int bx = blockIdx.x;   // along N
  const int by = blockIdx.y;   // along K
  const int tx = threadIdx.x & 31, ty = threadIdx.x >> 5;  // 32 x 8
  #pragma unroll
  for (int i = 0; i < 4; ++i){
    int r = by*32 + ty + i*8;   // k
    int c = bx*32 + tx;         // n
    t[ty + i*8][tx] = W[(long)r * N + c];
  }
  __syncthreads();
  #pragma unroll
  for (int i = 0; i < 4; ++i){
    int n = bx*32 + ty + i*8;
    int k = by*32 + tx;
    float v = t[tx][ty + i*8];
    u16 h, l; split2(v, h, l);
    WT[(long)n * 2 * K + k]     = h;
    WT[(long)n * 2 * K + K + k] = l;
  }
}

// ---------------------------------------------------------------------------
// Plain bf16 GEMM: 128x128 tile, BK=64, 4 waves (2x2), global_load_lds
// width-16 staging into T2-swizzled LDS (col_u16 ^= (row&7)<<3; source
// pre-swizzled so linear LDS writes land swizzled). b128 fragment reads are
// 2-way-conflict-free. m-major tile order for XCD L2 locality.
// MODE 0: C = ushort split-out (hi at col, lo at col+KH), ldc = 2*KH
// MODE 1: C = fp32, + bias + residual
// ---------------------------------------------------------------------------
template<int MODE>
__global__ __launch_bounds__(256)
void gemm_bf16(const u16* __restrict__ A, int lda,
               const u16* __restrict__ B, int ldb,
               void* __restrict__ Cv, int ldc, int KH,
               int K2, int nTN, int nwg8,
               const float* __restrict__ bias,
               const float* __restrict__ res, int ldres)
{
  int id = blockIdx.x;
  id = (id & 7) * nwg8 + (id >> 3);   // bijective XCD swizzle (nwg % 8 == 0)
  const int bm = (id / nTN) * 128;    // m-major: consecutive ids share bm
  const int bn = (id % nTN) * 128;

  const int tid = threadIdx.x, lane = tid & 63, w = tid >> 6;
  const int wm = w >> 1, wn = w & 1;
  const int r16 = lane & 15, g = lane >> 4;
  const int srow = lane >> 3;                         // 0..7 row in 8-row chunk
  const int scol = ((lane & 7) ^ srow) * 8;           // pre-swizzled source col

  __shared__ __align__(16) u16 As[128 * 64];
  __shared__ __align__(16) u16 Bs[128 * 64];

  f32x4 acc[4][4];
  #pragma unroll
  for (int i = 0; i < 4; ++i)
    #pragma unroll
    for (int j = 0; j < 4; ++j)
      acc[i][j] = (f32x4){0.f, 0.f, 0.f, 0.f};

  // swizzled read cols: col ^ ((row&7)<<3); row&7 == r16&7 for all frag rows
  const int sw = (r16 & 7) << 3;

  for (int kt = 0; kt < K2; kt += 64){
    #pragma unroll
    for (int i = 0; i < 4; ++i){
      const u16* src = A + (long)(bm + w*32 + i*8 + srow) * lda + kt + scol;
      __builtin_amdgcn_global_load_lds(
          (const __attribute__((address_space(1))) unsigned int*)src,
          (__attribute__((address_space(3))) unsigned int*)(As + (w*32 + i*8) * 64),
          16, 0, 0);
    }
    #pragma unroll
    for (int i = 0; i < 4; ++i){
      const u16* src = B + (long)(bn + w*32 + i*8 + srow) * ldb + kt + scol;
      __builtin_amdgcn_global_load_lds(
          (const __attribute__((address_space(1))) unsigned int*)src,
          (__attribute__((address_space(3))) unsigned int*)(Bs + (w*32 + i*8) * 64),
          16, 0, 0);
    }
    __syncthreads();

    #pragma unroll
    for (int ks = 0; ks < 2; ++ks){
      short8 a[4], b[4];
      #pragma unroll
      for (int mf = 0; mf < 4; ++mf){
        int row = wm*64 + mf*16 + r16;
        a[mf] = *(const short8*)&As[row * 64 + ((ks*32 + g*8) ^ sw)];
      }
      #pragma unroll
      for (int nf = 0; nf < 4; ++nf){
        int row = wn*64 + nf*16 + r16;
        b[nf] = *(const short8*)&Bs[row * 64 + ((ks*32 + g*8) ^ sw)];
      }
      #pragma unroll
      for (int mf = 0; mf < 4; ++mf)
        #pragma unroll
        for (int nf = 0; nf < 4; ++nf)
          acc[mf][nf] = mf16(a[mf], b[nf], acc[mf][nf]);
    }
    __syncthreads();
  }

  // epilogue: C/D layout col = lane&15, row = 4*(lane>>4)+reg
  #pragma unroll
  for (int mf = 0; mf < 4; ++mf){
    #pragma unroll
    for (int r = 0; r < 4; ++r){
      long grow = bm + wm*64 + mf*16 + 4*g + r;
      #pragma unroll
      for (int nf = 0; nf < 4; ++nf){
        int gcol = bn + wn*64 + nf*16 + r16;
        float v = acc[mf][nf][r];
        if (MODE == 0){
          u16* C = (u16*)Cv;
          u16 h, l; split2(v, h, l);
          C[grow * ldc + gcol]      = h;
          C[grow * ldc + KH + gcol] = l;
        } else {
          float* C = (float*)Cv;
          v += bias[gcol] + res[grow * (long)ldres + gcol];
          C[grow * ldc + gcol] = v;
        }
      }
    }
  }
}

// ---------------------------------------------------------------------------
// Round-1 split GEMM (kept for the small K/V and ip projections, M=77 / M=4).
// ---------------------------------------------------------------------------
template<int BIAS, int RES>
__global__ __launch_bounds__(256)
void gemm_split(const float* __restrict__ A, int lda, long strideAz, int M,
                const float* __restrict__ B0, const float* __restrict__ B1,
                int nsplit, int ldb,
                float* __restrict__ C, int ldc, long strideCz,
                int K,
                const float* __restrict__ bias,
                const float* __restrict__ res, int ldres)
{
  const int bn = blockIdx.x * 128;
  const int bm = blockIdx.y * 128;
  A += (long)blockIdx.z * strideAz;
  C += (long)blockIdx.z * strideCz;
  const float* B = B0; int bcol = bn;
  if (bn >= nsplit){ B = B1; bcol = bn - nsplit; }

  const int tid = threadIdx.x;
  const int lane = tid & 63, w = tid >> 6;
  const int wm = w >> 1, wn = w & 1;
  const int r16 = lane & 15, g = lane >> 4;

  __shared__ u16 Ah[128][36], Al[128][36];
  __shared__ u16 Bh[128][36], Bl[128][36];

  int mvalid = M - bm; if (mvalid > 128) mvalid = 128;
  int wv = mvalid - wm*64; wv = wv < 0 ? 0 : (wv > 64 ? 64 : wv);
  const int mfn = (wv + 15) >> 4;

  f32x4 acc[4][4];
  #pragma unroll
  for (int i = 0; i < 4; ++i)
    #pragma unroll
    for (int j = 0; j < 4; ++j)
      acc[i][j] = (f32x4){0.f, 0.f, 0.f, 0.f};

  const int arow = tid >> 3;
  const int acol = (tid & 7) << 2;
  const int brow = tid >> 5;
  const int bcol4 = (tid & 31) << 2;

  for (int kt = 0; kt < K; kt += 32){
    #pragma unroll
    for (int p = 0; p < 4; ++p){
      int r = p*32 + arow;
      float4 v = {0.f,0.f,0.f,0.f};
      if (bm + r < M) v = *(const float4*)(A + (long)(bm + r)*lda + kt + acol);
      us4 vh, vl; u16 hh, ll;
      split2(v.x, hh, ll); vh[0]=hh; vl[0]=ll;
      split2(v.y, hh, ll); vh[1]=hh; vl[1]=ll;
      split2(v.z, hh, ll); vh[2]=hh; vl[2]=ll;
      split2(v.w, hh, ll); vh[3]=hh; vl[3]=ll;
      *(us4*)&Ah[r][acol] = vh;
      *(us4*)&Al[r][acol] = vl;
    }
    #pragma unroll
    for (int p = 0; p < 4; ++p){
      int kk = p*8 + brow;
      float4 v = *(const float4*)(B + (long)(kt + kk)*ldb + bcol + bcol4);
      u16 hh, ll;
      split2(v.x, hh, ll); Bh[bcol4+0][kk]=hh; Bl[bcol4+0][kk]=ll;
      split2(v.y, hh, ll); Bh[bcol4+1][kk]=hh; Bl[bcol4+1][kk]=ll;
      split2(v.z, hh, ll); Bh[bcol4+2][kk]=hh; Bl[bcol4+2][kk]=ll;
      split2(v.w, hh, ll); Bh[bcol4+3][kk]=hh; Bl[bcol4+3][kk]=ll;
    }
    __syncthreads();

    Frag bh[4], bl[4];
    #pragma unroll
    for (int nf = 0; nf < 4; ++nf){
      const u16* p0 = &Bh[wn*64 + nf*16 + r16][4*g];
      bh[nf].u[0] = *(const u64t*)(p0);
      bh[nf].u[1] = *(const u64t*)(p0 + 16);
      const u16* p1 = &Bl[wn*64 + nf*16 + r16][4*g];
      bl[nf].u[0] = *(const u64t*)(p1);
      bl[nf].u[1] = *(const u64t*)(p1 + 16);
    }
    #pragma unroll
    for (int mf = 0; mf < 4; ++mf){
      if (mf < mfn){
        Frag ah, al;
        const u16* p0 = &Ah[wm*64 + mf*16 + r16][4*g];
        ah.u[0] = *(const u64t*)(p0);
        ah.u[1] = *(const u64t*)(p0 + 16);
        const u16* p1 = &Al[wm*64 + mf*16 + r16][4*g];
        al.u[0] = *(const u64t*)(p1);
        al.u[1] = *(const u64t*)(p1 + 16);
        #pragma unroll
        for (int nf = 0; nf < 4; ++nf){
          acc[mf][nf] = mf16(ah.s, bh[nf].s, acc[mf][nf]);
          acc[mf][nf] = mf16(ah.s, bl[nf].s, acc[mf][nf]);
          acc[mf][nf] = mf16(al.s, bh[nf].s, acc[mf][nf]);
        }
      }
    }
    __syncthreads();
  }

  #pragma unroll
  for (int mf = 0; mf < 4; ++mf){
    #pragma unroll
    for (int r = 0; r < 4; ++r){
      int grow = bm + wm*64 + mf*16 + 4*g + r;
      if (grow < M){
        #pragma unroll
        for (int nf = 0; nf < 4; ++nf){
          int gcol = bn + wn*64 + nf*16 + r16;
          float v = acc[mf][nf][r];
          if (BIAS) v += bias[gcol];
          if (RES)  v += res[(long)grow*ldres + gcol];
          C[(long)grow*ldc + gcol] = v;
        }
      }
    }
  }
}

// ---------------------------------------------------------------------------
// Fused dual attention. Q read as pre-split bf16 (M x 2560); output written
// pre-split bf16 (M x 2560) for the out-projection GEMM.
// ---------------------------------------------------------------------------
__global__ __launch_bounds__(256)
void attn_kernel(const u16* __restrict__ Qsp,   // (4*4096, 2560) split
                 const float* __restrict__ kvt, // (4,77,2560) [K|V] fp32
                 const float* __restrict__ ipb, // (4,4,2560)  fp32
                 u16* __restrict__ attn_sp)     // (4*4096, 2560) split out
{
  const int qt = blockIdx.x, h = blockIdx.y, b = blockIdx.z;
  const int tid = threadIdx.x, lane = tid & 63, w = tid >> 6;
  const int r16 = lane & 15, g = lane >> 4;
  const bool do_ip = (b & 1);
  const float scale = 0.125f;

  __shared__ u16 U0[96*68], U1[96*68];
  __shared__ u16 Vth[64*100], Vtl[64*100];
  __shared__ float ipk[4][64], ipv[4][64], pip[64][4];

  {
    int j  = tid >> 4;
    int d4 = (tid & 15) << 2;
    #pragma unroll
    for (int p = 0; p < 6; ++p){
      int jj = p*16 + j;
      float4 kv4 = {0.f,0.f,0.f,0.f}, vv4 = {0.f,0.f,0.f,0.f};
      if (jj < 77){
        const float* src = kvt + (long)(b*77 + jj)*2560 + h*64 + d4;
        kv4 = *(const float4*)(src);
        vv4 = *(const float4*)(src + 1280);
      }
      u16 hh, ll;
      us4 kh, kl;
      split2(kv4.x, hh, ll); kh[0]=hh; kl[0]=ll;
      split2(kv4.y, hh, ll); kh[1]=hh; kl[1]=ll;
      split2(kv4.z, hh, ll); kh[2]=hh; kl[2]=ll;
      split2(kv4.w, hh, ll); kh[3]=hh; kl[3]=ll;
      *(us4*)&U0[jj*68 + d4] = kh;
      *(us4*)&U1[jj*68 + d4] = kl;
      split2(vv4.x, hh, ll); Vth[(d4+0)*100 + jj]=hh; Vtl[(d4+0)*100 + jj]=ll;
      split2(vv4.y, hh, ll); Vth[(d4+1)*100 + jj]=hh; Vtl[(d4+1)*100 + jj]=ll;
      split2(vv4.z, hh, ll); Vth[(d4+2)*100 + jj]=hh; Vtl[(d4+2)*100 + jj]=ll;
      split2(vv4.w, hh, ll); Vth[(d4+3)*100 + jj]=hh; Vtl[(d4+3)*100 + jj]=ll;
    }
  }
  if (do_ip){
    int i = tid >> 6, d = tid & 63;
    const float* src = ipb + (long)(b*4 + i)*2560 + h*64 + d;
    ipk[i][d] = src[0];
    ipv[i][d] = src[1280];
  }
  __syncthreads();

  // ---- Q fragments direct from split-bf16 global ----
  Frag qh[2], ql[2];
  {
    const u16* qrow = Qsp + (long)(b*4096 + qt*64 + w*16 + r16)*2560 + h*64;
    #pragma unroll
    for (int ks = 0; ks < 2; ++ks){
      qh[ks].u[0] = *(const u64t*)(qrow + ks*32 + 4*g);
      qh[ks].u[1] = *(const u64t*)(qrow + ks*32 + 16 + 4*g);
      ql[ks].u[0] = *(const u64t*)(qrow + 1280 + ks*32 + 4*g);
      ql[ks].u[1] = *(const u64t*)(qrow + 1280 + ks*32 + 16 + 4*g);
    }
  }
  f32x4 sacc[6];
  #pragma unroll
  for (int nf = 0; nf < 6; ++nf) sacc[nf] = (f32x4){0.f,0.f,0.f,0.f};
  #pragma unroll
  for (int nf = 0; nf < 6; ++nf){
    #pragma unroll
    for (int ks = 0; ks < 2; ++ks){
      Frag kh, kl;
      const u16* p0 = &U0[(nf*16 + r16)*68 + ks*32 + 4*g];
      kh.u[0] = *(const u64t*)(p0);
      kh.u[1] = *(const u64t*)(p0 + 16);
      const u16* p1 = &U1[(nf*16 + r16)*68 + ks*32 + 4*g];
      kl.u[0] = *(const u64t*)(p1);
      kl.u[1] = *(const u64t*)(p1 + 16);
      sacc[nf] = mf16(qh[ks].s, kh.s, sacc[nf]);
      sacc[nf] = mf16(qh[ks].s, kl.s, sacc[nf]);
      sacc[nf] = mf16(ql[ks].s, kh.s, sacc[nf]);
    }
  }

  float mx[4] = {-1e30f,-1e30f,-1e30f,-1e30f};
  #pragma unroll
  for (int nf = 0; nf < 6; ++nf){
    if (nf*16 + r16 < 77){
      #pragma unroll
      for (int r = 0; r < 4; ++r) mx[r] = fmaxf(mx[r], sacc[nf][r]);
    }
  }
  #pragma unroll
  for (int off = 1; off < 16; off <<= 1){
    #pragma unroll
    for (int r = 0; r < 4; ++r) mx[r] = fmaxf(mx[r], __shfl_xor(mx[r], off));
  }
  float p[6][4];
  float sum[4] = {0.f,0.f,0.f,0.f};
  #pragma unroll
  for (int nf = 0; nf < 6; ++nf){
    bool valid = (nf*16 + r16 < 77);
    #pragma unroll
    for (int r = 0; r < 4; ++r){
      float e = valid ? __expf((sacc[nf][r] - mx[r]) * scale) : 0.f;
      p[nf][r] = e; sum[r] += e;
    }
  }
  #pragma unroll
  for (int off = 1; off < 16; off <<= 1){
    #pragma unroll
    for (int r = 0; r < 4; ++r) sum[r] += __shfl_xor(sum[r], off);
  }
  #pragma unroll
  for (int r = 0; r < 4; ++r) sum[r] = 1.f / sum[r];
  #pragma unroll
  for (int nf = 0; nf < 6; ++nf)
    #pragma unroll
    for (int r = 0; r < 4; ++r) p[nf][r] *= sum[r];

  if (do_ip){
    int rr = tid >> 2, ii = tid & 3;
    const u16* q2 = Qsp + (long)(b*4096 + qt*64 + rr)*2560 + h*64;
    float s = 0.f;
    #pragma unroll
    for (int d4 = 0; d4 < 64; d4 += 4){
      us4 hv = *(const us4*)(q2 + d4);
      us4 lv = *(const us4*)(q2 + 1280 + d4);
      #pragma unroll
      for (int i = 0; i < 4; ++i)
        s += (fromb(hv[i]) + fromb(lv[i])) * ipk[ii][d4 + i];
    }
    float m2 = fmaxf(s, __shfl_xor(s, 1)); m2 = fmaxf(m2, __shfl_xor(m2, 2));
    float e  = __expf((s - m2) * scale);
    float es = e + __shfl_xor(e, 1); es += __shfl_xor(es, 2);
    pip[rr][ii] = e / es;
  }

  __syncthreads();

  #pragma unroll
  for (int nf = 0; nf < 6; ++nf){
    int jc = nf*16 + r16;
    #pragma unroll
    for (int r = 0; r < 4; ++r){
      int qr = w*16 + 4*g + r;
      u16 hh, ll; split2(p[nf][r], hh, ll);
      U0[qr*100 + jc] = hh; U1[qr*100 + jc] = ll;
    }
  }
  __syncthreads();

  f32x4 oacc[4];
  #pragma unroll
  for (int nf = 0; nf < 4; ++nf) oacc[nf] = (f32x4){0.f,0.f,0.f,0.f};
  Frag ph[3], pl[3];
  #pragma unroll
  for (int ks = 0; ks < 3; ++ks){
    const u16* p0 = &U0[(w*16 + r16)*100 + ks*32 + 4*g];
    ph[ks].u[0] = *(const u64t*)(p0);
    ph[ks].u[1] = *(const u64t*)(p0 + 16);
    const u16* p1 = &U1[(w*16 + r16)*100 + ks*32 + 4*g];
    pl[ks].u[0] = *(const u64t*)(p1);
    pl[ks].u[1] = *(const u64t*)(p1 + 16);
  }
  #pragma unroll
  for (int nf = 0; nf < 4; ++nf){
    #pragma unroll
    for (int ks = 0; ks < 3; ++ks){
      Frag vh, vl;
      const u16* p0 = &Vth[(nf*16 + r16)*100 + ks*32 + 4*g];
      vh.u[0] = *(const u64t*)(p0);
      vh.u[1] = *(const u64t*)(p0 + 16);
      const u16* p1 = &Vtl[(nf*16 + r16)*100 + ks*32 + 4*g];
      vl.u[0] = *(const u64t*)(p1);
      vl.u[1] = *(const u64t*)(p1 + 16);
      oacc[nf] = mf16(ph[ks].s, vh.s, oacc[nf]);
      oacc[nf] = mf16(ph[ks].s, vl.s, oacc[nf]);
      oacc[nf] = mf16(pl[ks].s, vh.s, oacc[nf]);
    }
  }

  #pragma unroll
  for (int nf = 0; nf < 4; ++nf){
    int dv = nf*16 + r16;
    #pragma unroll
    for (int r = 0; r < 4; ++r){
      int lr = w*16 + 4*g + r;
      float val = oacc[nf][r];
      if (do_ip){
        val += pip[lr][0]*ipv[0][dv] + pip[lr][1]*ipv[1][dv]
             + pip[lr][2]*ipv[2][dv] + pip[lr][3]*ipv[3][dv];
      }
      u16 hh, ll; split2(val, hh, ll);
      long base = (long)(b*4096 + qt*64 + lr)*2560 + h*64 + dv;
      attn_sp[base]        = hh;
      attn_sp[base + 1280] = ll;
    }
  }
}

// ---------------------------------------------------------------------------
extern "C" void kernel_launch(void* const* d_in, const int* in_sizes, int n_in,
                              void* d_out, int out_size, void* d_ws, size_t ws_size,
                              hipStream_t stream)
{
  const float* hs   = (const float*)d_in[0];
  const float* ehs  = (const float*)d_in[1];
  const float* Wq   = (const float*)d_in[2];
  const float* Wk   = (const float*)d_in[3];
  const float* Wv   = (const float*)d_in[4];
  const float* Wkip = (const float*)d_in[5];
  const float* Wvip = (const float*)d_in[6];
  const float* Wout = (const float*)d_in[7];
  const float* bout = (const float*)d_in[8];
  float* out = (float*)d_out;

  // workspace layout (~100 MB): bufA reused as hs_sp then attn_sp
  u16* bufA  = (u16*)d_ws;                 // 16384 x 2560 bf16
  u16* WqT   = bufA + 16384L * 2560;       // 1280 x 2560
  u16* WoT   = WqT  + 1280L * 2560;        // 1280 x 2560
  float* kvt = (float*)(WoT + 1280L * 2560); // 4 x 77 x 2560
  float* ipb = kvt + 4L * 77 * 2560;         // 4 x 4 x 2560
  u16* Qsp   = (u16*)d_out;                // Q staged split in d_out

  dim3 blk(256);

  // 1. hs -> split (bufA)
  convert_split_rows<<<dim3(20480), blk, 0, stream>>>(hs, bufA, 1280);
  // 2. weight transpose+split
  transpose_split<<<dim3(40,40), blk, 0, stream>>>(Wq,   WqT, 1280, 1280);
  transpose_split<<<dim3(40,40), blk, 0, stream>>>(Wout, WoT, 1280, 1280);
  // 3. small projections (fp32 in, fp32 out)
  gemm_split<0,0><<<dim3(20,1,4), blk, 0, stream>>>(
      ehs, 2048, 81L*2048, 77, Wk, Wv, 1280, 1280,
      kvt, 2560, 77L*2560, 2048, nullptr, nullptr, 0);
  gemm_split<0,0><<<dim3(20,1,4), blk, 0, stream>>>(
      ehs + 77L*2048, 2048, 81L*2048, 4, Wkip, Wvip, 1280, 1280,
      ipb, 2560, 4L*2560, 2048, nullptr, nullptr, 0);
  // 4. Q projection: hs_sp @ WqT -> Qsp (split out, in d_out)
  gemm_bf16<0><<<dim3(1280), blk, 0, stream>>>(
      bufA, 2560, WqT, 2560, (void*)Qsp, 2560, 1280,
      2560, 10, 160, nullptr, nullptr, 0);
  // 5. fused dual attention -> attn_sp (bufA, overwrites hs_sp)
  attn_kernel<<<dim3(64,20,4), blk, 0, stream>>>(Qsp, kvt, ipb, bufA);
  // 6. out projection + bias + residual -> d_out (fp32)
  gemm_bf16<1><<<dim3(1280), blk, 0, stream>>>(
      bufA, 2560, WoT, 2560, (void*)out, 1280, 0,
      2560, 10, 160, bout, hs, 1280);
}

// Round 9
// 698.181 us; speedup vs baseline: 3.4218x; 1.3395x over previous
//
#include <hip/hip_runtime.h>

// IPAttnProcessor cross-modal fused pipeline for MI355X (gfx950).
// fp32 GEMMs emulated with K-concatenated split-bf16: x = hi + lo (bf16 each),
// stored as [hi | lo] along K. A_sp(M x 2K) @ W_spT(N x 2K)^T includes all four
// hi/lo cross terms in ONE plain bf16 GEMM.
// R4: T2 XOR-swizzle LDS (both-sides), b128 frag reads, m-major tile order.
// R6: small projections moved onto the same swizzled MFMA core (proj_kernel,
//     one dispatch for text+ip), weights pre-transposed+split; gemm_split
//     retired. Workspace region R0 time-shared: {WkvT,WipT,ehs_sp} -> hs_sp.

typedef __attribute__((ext_vector_type(8))) short short8;
typedef __attribute__((ext_vector_type(4))) float f32x4;
typedef __attribute__((ext_vector_type(4))) unsigned short us4;
typedef unsigned short u16;
typedef unsigned long long u64t;

__device__ __forceinline__ u16 bhi(float x){
  return (u16)(__builtin_bit_cast(unsigned int, x) >> 16);
}
__device__ __forceinline__ float fromb(u16 h){
  unsigned int u = ((unsigned int)h) << 16;
  return __builtin_bit_cast(float, u);
}
__device__ __forceinline__ void split2(float x, u16& h, u16& l){
  h = bhi(x);
  l = bhi(x - fromb(h));
}
__device__ __forceinline__ f32x4 mf16(short8 a, short8 b, f32x4 c){
  return __builtin_amdgcn_mfma_f32_16x16x32_bf16(a, b, c, 0, 0, 0);
}

union Frag { short8 s; u64t u[2]; };

// ---------------------------------------------------------------------------
// convert fp32 rows (M x K) -> split rows (M x 2K bf16): [m][k]=hi, [m][K+k]=lo
// ---------------------------------------------------------------------------
__global__ __launch_bounds__(256)
void convert_split_rows(const float* __restrict__ A, u16* __restrict__ Asp, int K)
{
  long idx = (long)blockIdx.x * 256 + threadIdx.x;
  long row = idx / (K / 4);
  int  k4  = (int)(idx % (K / 4)) * 4;
  float4 v = *(const float4*)(A + row * K + k4);
  us4 h, l; u16 hh, ll;
  split2(v.x, hh, ll); h[0]=hh; l[0]=ll;
  split2(v.y, hh, ll); h[1]=hh; l[1]=ll;
  split2(v.z, hh, ll); h[2]=hh; l[2]=ll;
  split2(v.w, hh, ll); h[3]=hh; l[3]=ll;
  *(us4*)(Asp + row * 2L * K + k4)     = h;
  *(us4*)(Asp + row * 2L * K + K + k4) = l;
}

// ---------------------------------------------------------------------------
// W (K x N fp32) -> WT_sp (N x 2K bf16): [n][k]=hi, [n][K+k]=lo (LDS transpose)
// ---------------------------------------------------------------------------
__device__ __forceinline__ void transpose_core(const float* __restrict__ W,
                                               u16* __restrict__ WT, int K, int N)
{
  __shared__ float t[32][33];
  const int bx = blockIdx.x;   // along N
  const int by = blockIdx.y;   // along K
  const int tx = threadIdx.x & 31, ty = threadIdx.x >> 5;  // 32 x 8
  #pragma unroll
  for (int i = 0; i < 4; ++i){
    int r = by*32 + ty + i*8;   // k
    int c = bx*32 + tx;         // n
    t[ty + i*8][tx] = W[(long)r * N + c];
  }
  __syncthreads();
  #pragma unroll
  for (int i = 0; i < 4; ++i){
    int n = bx*32 + ty + i*8;
    int k = by*32 + tx;
    float v = t[tx][ty + i*8];
    u16 h, l; split2(v, h, l);
    WT[(long)n * 2 * K + k]     = h;
    WT[(long)n * 2 * K + K + k] = l;
  }
}

__global__ __launch_bounds__(256)
void transpose_split(const float* __restrict__ W, u16* __restrict__ WT, int K, int N)
{
  transpose_core(W, WT, K, N);
}

// 4 KV-projection weights (each 2048 x 1280) in one dispatch, z selects.
__global__ __launch_bounds__(256)
void transpose_kv(const float* __restrict__ Wk,  const float* __restrict__ Wv,
                  const float* __restrict__ Wkip, const float* __restrict__ Wvip,
                  u16* __restrict__ WkvT, u16* __restrict__ WipT)
{
  const int z = blockIdx.z;
  const float* W = (z==0) ? Wk : (z==1) ? Wv : (z==2) ? Wkip : Wvip;
  u16* WT = ((z < 2) ? WkvT : WipT) + (long)(z & 1) * 1280 * 4096;
  transpose_core(W, WT, 2048, 1280);
}

// ---------------------------------------------------------------------------
// Shared bf16 GEMM core: 128x128 tile, BK=64, 4 waves (2x2), global_load_lds
// width-16 into T2-swizzled LDS (pre-swizzled source; swizzled b128 reads).
// Epilogue rows clamped to M (staging reads past M hit valid memory; their
// acc rows are discarded).
// MODE 0: C = u16 split-out (hi at col, lo at col+KH), ldc = 2*KH
// MODE 1: C = fp32 + bias + residual
// MODE 2: C = fp32 plain
// ---------------------------------------------------------------------------
template<int MODE>
__device__ __forceinline__ void gemm_core(
    const u16* __restrict__ A, int lda,
    const u16* __restrict__ B, int ldb,
    void* __restrict__ Cv, int ldc, int KH,
    int K2, int M, int bm, int bn,
    const float* __restrict__ bias,
    const float* __restrict__ res, int ldres)
{
  const int tid = threadIdx.x, lane = tid & 63, w = tid >> 6;
  const int wm = w >> 1, wn = w & 1;
  const int r16 = lane & 15, g = lane >> 4;
  const int srow = lane >> 3;                 // 0..7 row in 8-row chunk
  const int scol = ((lane & 7) ^ srow) * 8;   // pre-swizzled source col

  __shared__ __align__(16) u16 As[128 * 64];
  __shared__ __align__(16) u16 Bs[128 * 64];

  f32x4 acc[4][4];
  #pragma unroll
  for (int i = 0; i < 4; ++i)
    #pragma unroll
    for (int j = 0; j < 4; ++j)
      acc[i][j] = (f32x4){0.f, 0.f, 0.f, 0.f};

  const int sw = (r16 & 7) << 3;  // read-side swizzle

  for (int kt = 0; kt < K2; kt += 64){
    #pragma unroll
    for (int i = 0; i < 4; ++i){
      const u16* src = A + (long)(bm + w*32 + i*8 + srow) * lda + kt + scol;
      __builtin_amdgcn_global_load_lds(
          (const __attribute__((address_space(1))) unsigned int*)src,
          (__attribute__((address_space(3))) unsigned int*)(As + (w*32 + i*8) * 64),
          16, 0, 0);
    }
    #pragma unroll
    for (int i = 0; i < 4; ++i){
      const u16* src = B + (long)(bn + w*32 + i*8 + srow) * ldb + kt + scol;
      __builtin_amdgcn_global_load_lds(
          (const __attribute__((address_space(1))) unsigned int*)src,
          (__attribute__((address_space(3))) unsigned int*)(Bs + (w*32 + i*8) * 64),
          16, 0, 0);
    }
    __syncthreads();

    #pragma unroll
    for (int ks = 0; ks < 2; ++ks){
      short8 a[4], b[4];
      #pragma unroll
      for (int mf = 0; mf < 4; ++mf){
        int row = wm*64 + mf*16 + r16;
        a[mf] = *(const short8*)&As[row * 64 + ((ks*32 + g*8) ^ sw)];
      }
      #pragma unroll
      for (int nf = 0; nf < 4; ++nf){
        int row = wn*64 + nf*16 + r16;
        b[nf] = *(const short8*)&Bs[row * 64 + ((ks*32 + g*8) ^ sw)];
      }
      #pragma unroll
      for (int mf = 0; mf < 4; ++mf)
        #pragma unroll
        for (int nf = 0; nf < 4; ++nf)
          acc[mf][nf] = mf16(a[mf], b[nf], acc[mf][nf]);
    }
    __syncthreads();
  }

  // epilogue: C/D layout col = lane&15, row = 4*(lane>>4)+reg
  #pragma unroll
  for (int mf = 0; mf < 4; ++mf){
    #pragma unroll
    for (int r = 0; r < 4; ++r){
      long grow = bm + wm*64 + mf*16 + 4*g + r;
      if (grow < M){
        #pragma unroll
        for (int nf = 0; nf < 4; ++nf){
          int gcol = bn + wn*64 + nf*16 + r16;
          float v = acc[mf][nf][r];
          if (MODE == 0){
            u16* C = (u16*)Cv;
            u16 h, l; split2(v, h, l);
            C[grow * ldc + gcol]      = h;
            C[grow * ldc + KH + gcol] = l;
          } else if (MODE == 1){
            float* C = (float*)Cv;
            v += bias[gcol] + res[grow * (long)ldres + gcol];
            C[grow * ldc + gcol] = v;
          } else {
            float* C = (float*)Cv;
            C[grow * ldc + gcol] = v;
          }
        }
      }
    }
  }
}

template<int MODE>
__global__ __launch_bounds__(256)
void gemm_bf16(const u16* __restrict__ A, int lda,
               const u16* __restrict__ B, int ldb,
               void* __restrict__ Cv, int ldc, int KH,
               int K2, int nTN, int nwg8,
               const float* __restrict__ bias,
               const float* __restrict__ res, int ldres)
{
  int id = blockIdx.x;
  id = (id & 7) * nwg8 + (id >> 3);   // bijective XCD swizzle (nwg % 8 == 0)
  const int bm = (id / nTN) * 128;    // m-major: consecutive ids share bm
  const int bn = (id % nTN) * 128;
  gemm_core<MODE>(A, lda, B, ldb, Cv, ldc, KH, K2, 1 << 30, bm, bn, bias, res, ldres);
}

// ---------------------------------------------------------------------------
// Merged small projections: z<4 -> text K/V (M=77, B=WkvT), z>=4 -> ip (M=4,
// B=WipT). One 128x128 tile per (n-tile, z); epilogue M-clamped.
// ---------------------------------------------------------------------------
__global__ __launch_bounds__(256)
void proj_kernel(const u16* __restrict__ ehs_sp,
                 const u16* __restrict__ WkvT, const u16* __restrict__ WipT,
                 float* __restrict__ kvt, float* __restrict__ ipb)
{
  const int z = blockIdx.z;
  const int b = z & 3;
  const bool ip = (z >> 2) != 0;
  const u16* A = ehs_sp + (long)(b * 81 + (ip ? 77 : 0)) * 4096;
  const u16* B = ip ? WipT : WkvT;
  float* C = ip ? (ipb + (long)b * 4 * 2560) : (kvt + (long)b * 77 * 2560);
  const int M = ip ? 4 : 77;
  gemm_core<2>(A, 4096, B, 4096, (void*)C, 2560, 0, 4096, M,
               0, blockIdx.x * 128, nullptr, nullptr, 0);
}

// ---------------------------------------------------------------------------
// Fused dual attention. Q read as pre-split bf16 (M x 2560); output written
// pre-split bf16 (M x 2560) for the out-projection GEMM.
// ---------------------------------------------------------------------------
__global__ __launch_bounds__(256)
void attn_kernel(const u16* __restrict__ Qsp,   // (4*4096, 2560) split
                 const float* __restrict__ kvt, // (4,77,2560) [K|V] fp32
                 const float* __restrict__ ipb, // (4,4,2560)  fp32
                 u16* __restrict__ attn_sp)     // (4*4096, 2560) split out
{
  const int qt = blockIdx.x, h = blockIdx.y, b = blockIdx.z;
  const int tid = threadIdx.x, lane = tid & 63, w = tid >> 6;
  const int r16 = lane & 15, g = lane >> 4;
  const bool do_ip = (b & 1);
  const float scale = 0.125f;

  __shared__ u16 U0[96*68], U1[96*68];
  __shared__ u16 Vth[64*100], Vtl[64*100];
  __shared__ float ipk[4][64], ipv[4][64], pip[64][4];

  {
    int j  = tid >> 4;
    int d4 = (tid & 15) << 2;
    #pragma unroll
    for (int p = 0; p < 6; ++p){
      int jj = p*16 + j;
      float4 kv4 = {0.f,0.f,0.f,0.f}, vv4 = {0.f,0.f,0.f,0.f};
      if (jj < 77){
        const float* src = kvt + (long)(b*77 + jj)*2560 + h*64 + d4;
        kv4 = *(const float4*)(src);
        vv4 = *(const float4*)(src + 1280);
      }
      u16 hh, ll;
      us4 kh, kl;
      split2(kv4.x, hh, ll); kh[0]=hh; kl[0]=ll;
      split2(kv4.y, hh, ll); kh[1]=hh; kl[1]=ll;
      split2(kv4.z, hh, ll); kh[2]=hh; kl[2]=ll;
      split2(kv4.w, hh, ll); kh[3]=hh; kl[3]=ll;
      *(us4*)&U0[jj*68 + d4] = kh;
      *(us4*)&U1[jj*68 + d4] = kl;
      split2(vv4.x, hh, ll); Vth[(d4+0)*100 + jj]=hh; Vtl[(d4+0)*100 + jj]=ll;
      split2(vv4.y, hh, ll); Vth[(d4+1)*100 + jj]=hh; Vtl[(d4+1)*100 + jj]=ll;
      split2(vv4.z, hh, ll); Vth[(d4+2)*100 + jj]=hh; Vtl[(d4+2)*100 + jj]=ll;
      split2(vv4.w, hh, ll); Vth[(d4+3)*100 + jj]=hh; Vtl[(d4+3)*100 + jj]=ll;
    }
  }
  if (do_ip){
    int i = tid >> 6, d = tid & 63;
    const float* src = ipb + (long)(b*4 + i)*2560 + h*64 + d;
    ipk[i][d] = src[0];
    ipv[i][d] = src[1280];
  }
  __syncthreads();

  // ---- Q fragments direct from split-bf16 global ----
  Frag qh[2], ql[2];
  {
    const u16* qrow = Qsp + (long)(b*4096 + qt*64 + w*16 + r16)*2560 + h*64;
    #pragma unroll
    for (int ks = 0; ks < 2; ++ks){
      qh[ks].u[0] = *(const u64t*)(qrow + ks*32 + 4*g);
      qh[ks].u[1] = *(const u64t*)(qrow + ks*32 + 16 + 4*g);
      ql[ks].u[0] = *(const u64t*)(qrow + 1280 + ks*32 + 4*g);
      ql[ks].u[1] = *(const u64t*)(qrow + 1280 + ks*32 + 16 + 4*g);
    }
  }
  f32x4 sacc[6];
  #pragma unroll
  for (int nf = 0; nf < 6; ++nf) sacc[nf] = (f32x4){0.f,0.f,0.f,0.f};
  #pragma unroll
  for (int nf = 0; nf < 6; ++nf){
    #pragma unroll
    for (int ks = 0; ks < 2; ++ks){
      Frag kh, kl;
      const u16* p0 = &U0[(nf*16 + r16)*68 + ks*32 + 4*g];
      kh.u[0] = *(const u64t*)(p0);
      kh.u[1] = *(const u64t*)(p0 + 16);
      const u16* p1 = &U1[(nf*16 + r16)*68 + ks*32 + 4*g];
      kl.u[0] = *(const u64t*)(p1);
      kl.u[1] = *(const u64t*)(p1 + 16);
      sacc[nf] = mf16(qh[ks].s, kh.s, sacc[nf]);
      sacc[nf] = mf16(qh[ks].s, kl.s, sacc[nf]);
      sacc[nf] = mf16(ql[ks].s, kh.s, sacc[nf]);
    }
  }

  float mx[4] = {-1e30f,-1e30f,-1e30f,-1e30f};
  #pragma unroll
  for (int nf = 0; nf < 6; ++nf){
    if (nf*16 + r16 < 77){
      #pragma unroll
      for (int r = 0; r < 4; ++r) mx[r] = fmaxf(mx[r], sacc[nf][r]);
    }
  }
  #pragma unroll
  for (int off = 1; off < 16; off <<= 1){
    #pragma unroll
    for (int r = 0; r < 4; ++r) mx[r] = fmaxf(mx[r], __shfl_xor(mx[r], off));
  }
  float p[6][4];
  float sum[4] = {0.f,0.f,0.f,0.f};
  #pragma unroll
  for (int nf = 0; nf < 6; ++nf){
    bool valid = (nf*16 + r16 < 77);
    #pragma unroll
    for (int r = 0; r < 4; ++r){
      float e = valid ? __expf((sacc[nf][r] - mx[r]) * scale) : 0.f;
      p[nf][r] = e; sum[r] += e;
    }
  }
  #pragma unroll
  for (int off = 1; off < 16; off <<= 1){
    #pragma unroll
    for (int r = 0; r < 4; ++r) sum[r] += __shfl_xor(sum[r], off);
  }
  #pragma unroll
  for (int r = 0; r < 4; ++r) sum[r] = 1.f / sum[r];
  #pragma unroll
  for (int nf = 0; nf < 6; ++nf)
    #pragma unroll
    for (int r = 0; r < 4; ++r) p[nf][r] *= sum[r];

  if (do_ip){
    int rr = tid >> 2, ii = tid & 3;
    const u16* q2 = Qsp + (long)(b*4096 + qt*64 + rr)*2560 + h*64;
    float s = 0.f;
    #pragma unroll
    for (int d4 = 0; d4 < 64; d4 += 4){
      us4 hv = *(const us4*)(q2 + d4);
      us4 lv = *(const us4*)(q2 + 1280 + d4);
      #pragma unroll
      for (int i = 0; i < 4; ++i)
        s += (fromb(hv[i]) + fromb(lv[i])) * ipk[ii][d4 + i];
    }
    float m2 = fmaxf(s, __shfl_xor(s, 1)); m2 = fmaxf(m2, __shfl_xor(m2, 2));
    float e  = __expf((s - m2) * scale);
    float es = e + __shfl_xor(e, 1); es += __shfl_xor(es, 2);
    pip[rr][ii] = e / es;
  }

  __syncthreads();

  #pragma unroll
  for (int nf = 0; nf < 6; ++nf){
    int jc = nf*16 + r16;
    #pragma unroll
    for (int r = 0; r < 4; ++r){
      int qr = w*16 + 4*g + r;
      u16 hh, ll; split2(p[nf][r], hh, ll);
      U0[qr*100 + jc] = hh; U1[qr*100 + jc] = ll;
    }
  }
  __syncthreads();

  f32x4 oacc[4];
  #pragma unroll
  for (int nf = 0; nf < 4; ++nf) oacc[nf] = (f32x4){0.f,0.f,0.f,0.f};
  Frag ph[3], pl[3];
  #pragma unroll
  for (int ks = 0; ks < 3; ++ks){
    const u16* p0 = &U0[(w*16 + r16)*100 + ks*32 + 4*g];
    ph[ks].u[0] = *(const u64t*)(p0);
    ph[ks].u[1] = *(const u64t*)(p0 + 16);
    const u16* p1 = &U1[(w*16 + r16)*100 + ks*32 + 4*g];
    pl[ks].u[0] = *(const u64t*)(p1);
    pl[ks].u[1] = *(const u64t*)(p1 + 16);
  }
  #pragma unroll
  for (int nf = 0; nf < 4; ++nf){
    #pragma unroll
    for (int ks = 0; ks < 3; ++ks){
      Frag vh, vl;
      const u16* p0 = &Vth[(nf*16 + r16)*100 + ks*32 + 4*g];
      vh.u[0] = *(const u64t*)(p0);
      vh.u[1] = *(const u64t*)(p0 + 16);
      const u16* p1 = &Vtl[(nf*16 + r16)*100 + ks*32 + 4*g];
      vl.u[0] = *(const u64t*)(p1);
      vl.u[1] = *(const u64t*)(p1 + 16);
      oacc[nf] = mf16(ph[ks].s, vh.s, oacc[nf]);
      oacc[nf] = mf16(ph[ks].s, vl.s, oacc[nf]);
      oacc[nf] = mf16(pl[ks].s, vh.s, oacc[nf]);
    }
  }

  #pragma unroll
  for (int nf = 0; nf < 4; ++nf){
    int dv = nf*16 + r16;
    #pragma unroll
    for (int r = 0; r < 4; ++r){
      int lr = w*16 + 4*g + r;
      float val = oacc[nf][r];
      if (do_ip){
        val += pip[lr][0]*ipv[0][dv] + pip[lr][1]*ipv[1][dv]
             + pip[lr][2]*ipv[2][dv] + pip[lr][3]*ipv[3][dv];
      }
      u16 hh, ll; split2(val, hh, ll);
      long base = (long)(b*4096 + qt*64 + lr)*2560 + h*64 + dv;
      attn_sp[base]        = hh;
      attn_sp[base + 1280] = ll;
    }
  }
}

// ---------------------------------------------------------------------------
extern "C" void kernel_launch(void* const* d_in, const int* in_sizes, int n_in,
                              void* d_out, int out_size, void* d_ws, size_t ws_size,
                              hipStream_t stream)
{
  const float* hs   = (const float*)d_in[0];
  const float* ehs  = (const float*)d_in[1];
  const float* Wq   = (const float*)d_in[2];
  const float* Wk   = (const float*)d_in[3];
  const float* Wv   = (const float*)d_in[4];
  const float* Wkip = (const float*)d_in[5];
  const float* Wvip = (const float*)d_in[6];
  const float* Wout = (const float*)d_in[7];
  const float* bout = (const float*)d_in[8];
  float* out = (float*)d_out;

  // workspace (~100.3 MB):
  //   R0 (bufA, 16384x2560 u16 = 84 MB): phase 1 = {WkvT | WipT | ehs_sp},
  //     phase 2 = hs_sp (overwrites), phase 3 = attn_sp.
  //   then WqT, WoT (1280x2560 u16 each), kvt fp32, ipb fp32.
  u16* bufA    = (u16*)d_ws;
  u16* WkvT    = bufA;                       // 2560 x 4096 u16 (21 MB)
  u16* WipT    = bufA + 2560L * 4096;        // 2560 x 4096 u16 (21 MB)
  u16* ehs_sp  = WipT + 2560L * 4096;        // 324 x 4096 u16 (2.7 MB)
  u16* WqT     = bufA + 16384L * 2560;       // 1280 x 2560
  u16* WoT     = WqT  + 1280L * 2560;        // 1280 x 2560
  float* kvt   = (float*)(WoT + 1280L * 2560); // 4 x 77 x 2560
  float* ipb   = kvt + 4L * 77 * 2560;         // 4 x 4 x 2560
  u16* Qsp     = (u16*)d_out;                // Q staged split in d_out

  dim3 blk(256);

  // --- phase 1: small projections on the MFMA core ---
  transpose_kv<<<dim3(40,64,4), blk, 0, stream>>>(Wk, Wv, Wkip, Wvip, WkvT, WipT);
  convert_split_rows<<<dim3(648), blk, 0, stream>>>(ehs, ehs_sp, 2048);
  proj_kernel<<<dim3(20,1,8), blk, 0, stream>>>(ehs_sp, WkvT, WipT, kvt, ipb);

  // --- phase 2: big GEMMs (R0 becomes hs_sp) ---
  convert_split_rows<<<dim3(20480), blk, 0, stream>>>(hs, bufA, 1280);
  transpose_split<<<dim3(40,40), blk, 0, stream>>>(Wq,   WqT, 1280, 1280);
  transpose_split<<<dim3(40,40), blk, 0, stream>>>(Wout, WoT, 1280, 1280);
  gemm_bf16<0><<<dim3(1280), blk, 0, stream>>>(
      bufA, 2560, WqT, 2560, (void*)Qsp, 2560, 1280,
      2560, 10, 160, nullptr, nullptr, 0);

  // --- phase 3: attention (R0 becomes attn_sp) + out projection ---
  attn_kernel<<<dim3(64,20,4), blk, 0, stream>>>(Qsp, kvt, ipb, bufA);
  gemm_bf16<1><<<dim3(1280), blk, 0, stream>>>(
      bufA, 2560, WoT, 2560, (void*)out, 1280, 0,
      2560, 10, 160, bout, hs, 1280);
}